// Round 1
// baseline (1158.996 us; speedup 1.0000x reference)
//
#include <hip/hip_runtime.h>

// Problem constants (match reference)
#define NN 20000   // nodes
#define BB 16      // batch
#define FF 64      // input feature dim
#define CD 1024    // BB*FF channels per node
#define EE 640000  // edges
#define OD 64      // output dim
#define KM 192     // FF * M  (M = 3 Chebyshev terms)

// ws layout: [0, NN*CD*4) = x1  (82 MB, internal layout x1[n][b*64+f]);
//            then NN+1 ints of row_ptr.

__global__ void build_rowptr_k(const int* __restrict__ rows, int* __restrict__ rp) {
    int r = blockIdx.x * blockDim.x + threadIdx.x;
    if (r > NN) return;
    // lower_bound over sorted rows
    int lo = 0, hi = EE;
    while (lo < hi) {
        int mid = (lo + hi) >> 1;
        if (rows[mid] < r) lo = mid + 1; else hi = mid;
    }
    rp[r] = lo;
}

// x1[n, b*64+f] = sum_e vals[e] * inputs[b, cols[e], f]
__global__ __launch_bounds__(256) void spmm1_k(
    const float* __restrict__ inputs, const int* __restrict__ cols,
    const float* __restrict__ vals, const int* __restrict__ rp,
    float* __restrict__ x1) {
    int n = blockIdx.x;
    int t = threadIdx.x;
    int b = t >> 4;           // c' = 4t ; b = c'/64
    int f = (t & 15) << 2;    // f = c'%64
    int e0 = rp[n], e1 = rp[n + 1];
    const float* src = inputs + (size_t)b * NN * FF + f;
    float4 acc = make_float4(0.f, 0.f, 0.f, 0.f);
    for (int e = e0; e < e1; ++e) {
        int c = cols[e];
        float v = vals[e];
        float4 xv = *(const float4*)(src + (size_t)c * FF);
        acc.x += v * xv.x; acc.y += v * xv.y; acc.z += v * xv.z; acc.w += v * xv.w;
    }
    *(float4*)(x1 + (size_t)n * CD + (t << 2)) = acc;
}

// Fused: x2 = 2*A@x1 - x0 (registers), then per-node [16 x 192] @ [192 x 64] GEMM.
__global__ __launch_bounds__(256) void spmm2_gemm_k(
    const float* __restrict__ inputs, const int* __restrict__ cols,
    const float* __restrict__ vals, const int* __restrict__ rp,
    const float* __restrict__ x1, const float* __restrict__ W,
    const float* __restrict__ bias, float* __restrict__ out) {
    __shared__ float xs[BB][KM + 4];  // +4 pad: avoid 4-way bank alias on xs[b][k]
    __shared__ float wL[KM][OD];      // 48 KB
    __shared__ float bL[OD];

    int n = blockIdx.x;
    int t = threadIdx.x;

    // cooperative W load: 192*64/4 = 3072 float4, 12 per thread
    for (int i = t; i < (KM * OD) / 4; i += 256)
        ((float4*)wL)[i] = ((const float4*)W)[i];
    if (t < OD) bL[t] = bias[t];

    int b = t >> 4;
    int f = (t & 15) << 2;
    int e0 = rp[n], e1 = rp[n + 1];

    float4 acc = make_float4(0.f, 0.f, 0.f, 0.f);
    const float* x1base = x1 + (size_t)(t << 2);
    for (int e = e0; e < e1; ++e) {
        int c = cols[e];
        float v = vals[e];
        float4 xv = *(const float4*)(x1base + (size_t)c * CD);
        acc.x += v * xv.x; acc.y += v * xv.y; acc.z += v * xv.z; acc.w += v * xv.w;
    }

    float4 x0v = *(const float4*)(inputs + ((size_t)b * NN + n) * FF + f);
    float4 x1v = *(const float4*)(x1 + (size_t)n * CD + (t << 2));
    float4 x2v = make_float4(2.f * acc.x - x0v.x, 2.f * acc.y - x0v.y,
                             2.f * acc.z - x0v.z, 2.f * acc.w - x0v.w);

    // reference row layout: k = f*3 + m  (m: 0=x0, 1=x1, 2=x2)
    xs[b][(f + 0) * 3 + 0] = x0v.x; xs[b][(f + 0) * 3 + 1] = x1v.x; xs[b][(f + 0) * 3 + 2] = x2v.x;
    xs[b][(f + 1) * 3 + 0] = x0v.y; xs[b][(f + 1) * 3 + 1] = x1v.y; xs[b][(f + 1) * 3 + 2] = x2v.y;
    xs[b][(f + 2) * 3 + 0] = x0v.z; xs[b][(f + 2) * 3 + 1] = x1v.z; xs[b][(f + 2) * 3 + 2] = x2v.z;
    xs[b][(f + 3) * 3 + 0] = x0v.w; xs[b][(f + 3) * 3 + 1] = x1v.w; xs[b][(f + 3) * 3 + 2] = x2v.w;
    __syncthreads();

    // each thread: output row b (= t>>4), 4 output cols o..o+3
    int o = (t & 15) << 2;
    float4 r = make_float4(bL[o], bL[o + 1], bL[o + 2], bL[o + 3]);
    #pragma unroll 4
    for (int k = 0; k < KM; ++k) {
        float xv = xs[b][k];
        float4 w4 = *(const float4*)&wL[k][o];
        r.x += xv * w4.x; r.y += xv * w4.y; r.z += xv * w4.z; r.w += xv * w4.w;
    }
    // out row = b*NN + n (matches [B,N,F,M] -> [B*N, F*M] reshape)
    *(float4*)(out + ((size_t)b * NN + n) * OD + o) = r;
}

extern "C" void kernel_launch(void* const* d_in, const int* in_sizes, int n_in,
                              void* d_out, int out_size, void* d_ws, size_t ws_size,
                              hipStream_t stream) {
    const float* inputs  = (const float*)d_in[0];
    const int*   sp_rows = (const int*)d_in[1];
    const int*   sp_cols = (const int*)d_in[2];
    const float* sp_vals = (const float*)d_in[3];
    const float* weight  = (const float*)d_in[4];
    const float* biases  = (const float*)d_in[5];
    float* out = (float*)d_out;

    float* x1 = (float*)d_ws;
    int* rp = (int*)((char*)d_ws + (size_t)NN * CD * sizeof(float));

    build_rowptr_k<<<(NN + 256) / 256, 256, 0, stream>>>(sp_rows, rp);
    spmm1_k<<<NN, 256, 0, stream>>>(inputs, sp_cols, sp_vals, rp, x1);
    spmm2_gemm_k<<<NN, 256, 0, stream>>>(inputs, sp_cols, sp_vals, rp, x1,
                                         weight, biases, out);
}

// Round 2
// 639.527 us; speedup vs baseline: 1.8123x; 1.8123x over previous
//
#include <hip/hip_runtime.h>

#define NN 20000   // nodes
#define EE 640000  // edges
#define CAP 5120   // LDS edge-cache capacity (also throttles to 4 blocks/CU: 40KB)

__device__ __forceinline__ unsigned bf16rn(float x) {
    unsigned u = __float_as_uint(x);
    return (u + 0x7FFFu + ((u >> 16) & 1u)) >> 16;
}
__device__ __forceinline__ unsigned pack2(float a, float b) {
    return bf16rn(a) | (bf16rn(b) << 16);
}
__device__ __forceinline__ float bflo(unsigned u) { return __uint_as_float(u << 16); }
__device__ __forceinline__ float bfhi(unsigned u) { return __uint_as_float(u & 0xFFFF0000u); }

__global__ void build_rowptr_k(const int* __restrict__ rows, int* __restrict__ rp) {
    int r = blockIdx.x * blockDim.x + threadIdx.x;
    if (r > NN) return;
    int lo = 0, hi = EE;
    while (lo < hi) {
        int mid = (lo + hi) >> 1;
        if (rows[mid] < r) lo = mid + 1; else hi = mid;
    }
    rp[r] = lo;
}

// y1[n][c] (bf16, c = b*64+f) = sum_e vals[e] * inputs[b, cols[e], f]
// grid (625 chunks, 32 slices of 32 fp32 channels); slice working set 2.56MB -> L2
__global__ __launch_bounds__(256) void spmm1_k(
    const float* __restrict__ inputs, const int* __restrict__ cols,
    const float* __restrict__ vals, const int* __restrict__ rp,
    unsigned* __restrict__ y1 /* bf16 pairs, 512 words/node */) {
    __shared__ int   lc[CAP];
    __shared__ float lv[CAP];
    int s = blockIdx.y, t = threadIdx.x;
    int n0 = blockIdx.x * 32;
    int eBase = rp[n0];
    int eCap = min(rp[n0 + 32], eBase + CAP);
    for (int i = eBase + t; i < eCap; i += 256) { lc[i - eBase] = cols[i]; lv[i - eBase] = vals[i]; }
    __syncthreads();

    int node = n0 + (t >> 3);
    int ch = (t & 7) * 4;                       // 8 threads/node x 4 fp32 ch
    const float* sp = inputs + (size_t)(s >> 1) * NN * 64 + (s & 1) * 32 + ch;
    int e0 = rp[node], e1 = rp[node + 1];
    int eL = min(e1, eCap);
    float4 acc = make_float4(0.f, 0.f, 0.f, 0.f);
    #pragma unroll 4
    for (int e = e0; e < eL; ++e) {
        int c = lc[e - eBase]; float v = lv[e - eBase];
        float4 xv = *(const float4*)(sp + (size_t)c * 64);
        acc.x += v * xv.x; acc.y += v * xv.y; acc.z += v * xv.z; acc.w += v * xv.w;
    }
    for (int e = eL; e < e1; ++e) {             // overflow fallback (statistically never)
        int c = cols[e]; float v = vals[e];
        float4 xv = *(const float4*)(sp + (size_t)c * 64);
        acc.x += v * xv.x; acc.y += v * xv.y; acc.z += v * xv.z; acc.w += v * xv.w;
    }
    uint2 o; o.x = pack2(acc.x, acc.y); o.y = pack2(acc.z, acc.w);
    *(uint2*)(y1 + (size_t)node * 512 + s * 16 + (t & 7) * 2) = o;
}

// y2 = A @ y1 (bf16 in, bf16 out). grid (625, 16 slices of 64 bf16 channels = 128B)
__global__ __launch_bounds__(256) void spmm2_k(
    const unsigned* __restrict__ y1, const int* __restrict__ cols,
    const float* __restrict__ vals, const int* __restrict__ rp,
    unsigned* __restrict__ y2) {
    __shared__ int   lc[CAP];
    __shared__ float lv[CAP];
    int s = blockIdx.y, t = threadIdx.x;
    int n0 = blockIdx.x * 32;
    int eBase = rp[n0];
    int eCap = min(rp[n0 + 32], eBase + CAP);
    for (int i = eBase + t; i < eCap; i += 256) { lc[i - eBase] = cols[i]; lv[i - eBase] = vals[i]; }
    __syncthreads();

    int node = n0 + (t >> 3);
    const unsigned* sp = y1 + s * 32 + (t & 7) * 4;   // 8 threads/node x 8 bf16 ch (16B)
    int e0 = rp[node], e1 = rp[node + 1];
    int eL = min(e1, eCap);
    float a0 = 0, a1 = 0, a2 = 0, a3 = 0, a4 = 0, a5 = 0, a6 = 0, a7 = 0;
    #pragma unroll 2
    for (int e = e0; e < eL; ++e) {
        int c = lc[e - eBase]; float v = lv[e - eBase];
        uint4 w = *(const uint4*)(sp + (size_t)c * 512);
        a0 += v * bflo(w.x); a1 += v * bfhi(w.x);
        a2 += v * bflo(w.y); a3 += v * bfhi(w.y);
        a4 += v * bflo(w.z); a5 += v * bfhi(w.z);
        a6 += v * bflo(w.w); a7 += v * bfhi(w.w);
    }
    for (int e = eL; e < e1; ++e) {
        int c = cols[e]; float v = vals[e];
        uint4 w = *(const uint4*)(sp + (size_t)c * 512);
        a0 += v * bflo(w.x); a1 += v * bfhi(w.x);
        a2 += v * bflo(w.y); a3 += v * bfhi(w.y);
        a4 += v * bflo(w.z); a5 += v * bfhi(w.z);
        a6 += v * bflo(w.w); a7 += v * bfhi(w.w);
    }
    uint4 o;
    o.x = pack2(a0, a1); o.y = pack2(a2, a3); o.z = pack2(a4, a5); o.w = pack2(a6, a7);
    *(uint4*)(y2 + (size_t)node * 512 + s * 32 + (t & 7) * 4) = o;
}

// out[b*N+n][o] = sum_k xs[k] * Wmod[k][o] + bias, xs rows = [x0|y1|y2] interleaved,
// Wmod = [W0-W2, W1, 2*W2] (Chebyshev x2=2*y2-x0 folded into weights).
// 4 nodes/block, 64 rows x 64 cols, 4x4 register tile/thread, W k-halved for 2 blocks/CU.
__global__ __launch_bounds__(256) void gemm_k(
    const float* __restrict__ inputs, const unsigned* __restrict__ y1,
    const unsigned* __restrict__ y2, const float* __restrict__ W,
    const float* __restrict__ bias, float* __restrict__ out) {
    __shared__ float xs[64][196];   // 64 rows x 192k (+4 pad)
    __shared__ float wl[96][64];    // half of Wmod
    __shared__ float bl[64];

    int t = threadIdx.x;
    int n0 = blockIdx.x * 4;

    // ---- stage xs: 4 threads/row, 16 f's each ----
    {
        int row = t >> 2;              // nl*16 + b
        int nl = row >> 4, b = row & 15;
        int n = n0 + nl;
        int fq = (t & 3) * 16;
        const float* xp = inputs + ((size_t)b * NN + n) * 64 + fq;
        const unsigned* p1 = y1 + (size_t)n * 512 + b * 32 + (fq >> 1);
        const unsigned* p2 = y2 + (size_t)n * 512 + b * 32 + (fq >> 1);
        float xv[16], v1[16], v2[16];
        *(float4*)&xv[0]  = *(const float4*)(xp + 0);
        *(float4*)&xv[4]  = *(const float4*)(xp + 4);
        *(float4*)&xv[8]  = *(const float4*)(xp + 8);
        *(float4*)&xv[12] = *(const float4*)(xp + 12);
        uint4 u0 = *(const uint4*)p1, u1 = *(const uint4*)(p1 + 4);
        v1[0]=bflo(u0.x); v1[1]=bfhi(u0.x); v1[2]=bflo(u0.y); v1[3]=bfhi(u0.y);
        v1[4]=bflo(u0.z); v1[5]=bfhi(u0.z); v1[6]=bflo(u0.w); v1[7]=bfhi(u0.w);
        v1[8]=bflo(u1.x); v1[9]=bfhi(u1.x); v1[10]=bflo(u1.y); v1[11]=bfhi(u1.y);
        v1[12]=bflo(u1.z); v1[13]=bfhi(u1.z); v1[14]=bflo(u1.w); v1[15]=bfhi(u1.w);
        uint4 w0 = *(const uint4*)p2, w1 = *(const uint4*)(p2 + 4);
        v2[0]=bflo(w0.x); v2[1]=bfhi(w0.x); v2[2]=bflo(w0.y); v2[3]=bfhi(w0.y);
        v2[4]=bflo(w0.z); v2[5]=bfhi(w0.z); v2[6]=bflo(w0.w); v2[7]=bfhi(w0.w);
        v2[8]=bflo(w1.x); v2[9]=bfhi(w1.x); v2[10]=bflo(w1.y); v2[11]=bfhi(w1.y);
        v2[12]=bflo(w1.z); v2[13]=bfhi(w1.z); v2[14]=bflo(w1.w); v2[15]=bfhi(w1.w);
        #pragma unroll
        for (int j = 0; j < 16; ++j) {
            int base = (fq + j) * 3;
            xs[row][base + 0] = xv[j];
            xs[row][base + 1] = v1[j];
            xs[row][base + 2] = v2[j];
        }
    }
    if (t < 64) bl[t] = bias[t];
    // ---- Wmod half 0 (k = 0..95) ----
    for (int i = t; i < 6144; i += 256) {
        int lk = i >> 6, o = i & 63;
        int m = lk - (lk / 3) * 3;
        float w = W[lk * 64 + o];
        if (m == 0) w -= W[(lk + 2) * 64 + o];
        else if (m == 2) w += w;
        wl[lk][o] = w;
    }
    __syncthreads();

    int rg = t >> 4, cg = t & 15;
    int r0 = rg * 4, o0 = cg * 4;
    float4 bias4 = *(float4*)&bl[o0];
    float4 acc0 = bias4, acc1 = bias4, acc2 = bias4, acc3 = bias4;

    #pragma unroll 2
    for (int k4 = 0; k4 < 96; k4 += 4) {
        float4 x0v = *(float4*)&xs[r0 + 0][k4];
        float4 x1v = *(float4*)&xs[r0 + 1][k4];
        float4 x2v = *(float4*)&xs[r0 + 2][k4];
        float4 x3v = *(float4*)&xs[r0 + 3][k4];
        float4 w0v = *(float4*)&wl[k4 + 0][o0];
        float4 w1v = *(float4*)&wl[k4 + 1][o0];
        float4 w2v = *(float4*)&wl[k4 + 2][o0];
        float4 w3v = *(float4*)&wl[k4 + 3][o0];
        acc0.x += x0v.x*w0v.x + x0v.y*w1v.x + x0v.z*w2v.x + x0v.w*w3v.x;
        acc0.y += x0v.x*w0v.y + x0v.y*w1v.y + x0v.z*w2v.y + x0v.w*w3v.y;
        acc0.z += x0v.x*w0v.z + x0v.y*w1v.z + x0v.z*w2v.z + x0v.w*w3v.z;
        acc0.w += x0v.x*w0v.w + x0v.y*w1v.w + x0v.z*w2v.w + x0v.w*w3v.w;
        acc1.x += x1v.x*w0v.x + x1v.y*w1v.x + x1v.z*w2v.x + x1v.w*w3v.x;
        acc1.y += x1v.x*w0v.y + x1v.y*w1v.y + x1v.z*w2v.y + x1v.w*w3v.y;
        acc1.z += x1v.x*w0v.z + x1v.y*w1v.z + x1v.z*w2v.z + x1v.w*w3v.z;
        acc1.w += x1v.x*w0v.w + x1v.y*w1v.w + x1v.z*w2v.w + x1v.w*w3v.w;
        acc2.x += x2v.x*w0v.x + x2v.y*w1v.x + x2v.z*w2v.x + x2v.w*w3v.x;
        acc2.y += x2v.x*w0v.y + x2v.y*w1v.y + x2v.z*w2v.y + x2v.w*w3v.y;
        acc2.z += x2v.x*w0v.z + x2v.y*w1v.z + x2v.z*w2v.z + x2v.w*w3v.z;
        acc2.w += x2v.x*w0v.w + x2v.y*w1v.w + x2v.z*w2v.w + x2v.w*w3v.w;
        acc3.x += x3v.x*w0v.x + x3v.y*w1v.x + x3v.z*w2v.x + x3v.w*w3v.x;
        acc3.y += x3v.x*w0v.y + x3v.y*w1v.y + x3v.z*w2v.y + x3v.w*w3v.y;
        acc3.z += x3v.x*w0v.z + x3v.y*w1v.z + x3v.z*w2v.z + x3v.w*w3v.z;
        acc3.w += x3v.x*w0v.w + x3v.y*w1v.w + x3v.z*w2v.w + x3v.w*w3v.w;
    }
    __syncthreads();
    // ---- Wmod half 1 (k = 96..191) ----
    for (int i = t; i < 6144; i += 256) {
        int lk = i >> 6, o = i & 63;
        int m = lk - (lk / 3) * 3;
        int gk = 96 + lk;
        float w = W[gk * 64 + o];
        if (m == 0) w -= W[(gk + 2) * 64 + o];
        else if (m == 2) w += w;
        wl[lk][o] = w;
    }
    __syncthreads();
    #pragma unroll 2
    for (int k4 = 0; k4 < 96; k4 += 4) {
        float4 x0v = *(float4*)&xs[r0 + 0][96 + k4];
        float4 x1v = *(float4*)&xs[r0 + 1][96 + k4];
        float4 x2v = *(float4*)&xs[r0 + 2][96 + k4];
        float4 x3v = *(float4*)&xs[r0 + 3][96 + k4];
        float4 w0v = *(float4*)&wl[k4 + 0][o0];
        float4 w1v = *(float4*)&wl[k4 + 1][o0];
        float4 w2v = *(float4*)&wl[k4 + 2][o0];
        float4 w3v = *(float4*)&wl[k4 + 3][o0];
        acc0.x += x0v.x*w0v.x + x0v.y*w1v.x + x0v.z*w2v.x + x0v.w*w3v.x;
        acc0.y += x0v.x*w0v.y + x0v.y*w1v.y + x0v.z*w2v.y + x0v.w*w3v.y;
        acc0.z += x0v.x*w0v.z + x0v.y*w1v.z + x0v.z*w2v.z + x0v.w*w3v.z;
        acc0.w += x0v.x*w0v.w + x0v.y*w1v.w + x0v.z*w2v.w + x0v.w*w3v.w;
        acc1.x += x1v.x*w0v.x + x1v.y*w1v.x + x1v.z*w2v.x + x1v.w*w3v.x;
        acc1.y += x1v.x*w0v.y + x1v.y*w1v.y + x1v.z*w2v.y + x1v.w*w3v.y;
        acc1.z += x1v.x*w0v.z + x1v.y*w1v.z + x1v.z*w2v.z + x1v.w*w3v.z;
        acc1.w += x1v.x*w0v.w + x1v.y*w1v.w + x1v.z*w2v.w + x1v.w*w3v.w;
        acc2.x += x2v.x*w0v.x + x2v.y*w1v.x + x2v.z*w2v.x + x2v.w*w3v.x;
        acc2.y += x2v.x*w0v.y + x2v.y*w1v.y + x2v.z*w2v.y + x2v.w*w3v.y;
        acc2.z += x2v.x*w0v.z + x2v.y*w1v.z + x2v.z*w2v.z + x2v.w*w3v.z;
        acc2.w += x2v.x*w0v.w + x2v.y*w1v.w + x2v.z*w2v.w + x2v.w*w3v.w;
        acc3.x += x3v.x*w0v.x + x3v.y*w1v.x + x3v.z*w2v.x + x3v.w*w3v.x;
        acc3.y += x3v.x*w0v.y + x3v.y*w1v.y + x3v.z*w2v.y + x3v.w*w3v.y;
        acc3.z += x3v.x*w0v.z + x3v.y*w1v.z + x3v.z*w2v.z + x3v.w*w3v.z;
        acc3.w += x3v.x*w0v.w + x3v.y*w1v.w + x3v.z*w2v.w + x3v.w*w3v.w;
    }

    float4 accs[4] = {acc0, acc1, acc2, acc3};
    #pragma unroll
    for (int i = 0; i < 4; ++i) {
        int r = r0 + i;
        int b = r & 15, nl = r >> 4;
        *(float4*)(out + ((size_t)b * NN + (n0 + nl)) * 64 + o0) = accs[i];
    }
}

extern "C" void kernel_launch(void* const* d_in, const int* in_sizes, int n_in,
                              void* d_out, int out_size, void* d_ws, size_t ws_size,
                              hipStream_t stream) {
    const float* inputs  = (const float*)d_in[0];
    const int*   sp_rows = (const int*)d_in[1];
    const int*   sp_cols = (const int*)d_in[2];
    const float* sp_vals = (const float*)d_in[3];
    const float* weight  = (const float*)d_in[4];
    const float* biases  = (const float*)d_in[5];
    float* out = (float*)d_out;

    unsigned* y1 = (unsigned*)d_ws;                       // 20000*512 words = 41 MB
    unsigned* y2 = y1 + (size_t)NN * 512;                 // 41 MB
    int* rp = (int*)(y2 + (size_t)NN * 512);              // 80 KB

    build_rowptr_k<<<(NN + 256) / 256, 256, 0, stream>>>(sp_rows, rp);
    spmm1_k<<<dim3(625, 32), 256, 0, stream>>>(inputs, sp_cols, sp_vals, rp, y1);
    spmm2_k<<<dim3(625, 16), 256, 0, stream>>>(y1, sp_cols, sp_vals, rp, y2);
    gemm_k<<<5000, 256, 0, stream>>>(inputs, y1, y2, weight, biases, out);
}

// Round 3
// 437.855 us; speedup vs baseline: 2.6470x; 1.4606x over previous
//
#include <hip/hip_runtime.h>

#define NN 20000   // nodes
#define EE 640000  // edges
#define CAP 2048   // LDS edge-cache (int2) = 16 KB -> no occupancy throttle
#define WTP 200    // padded k-stride of transposed weight (breaks bank conflict)

typedef __attribute__((ext_vector_type(8))) short short8;
typedef __attribute__((ext_vector_type(4))) float float4v;

__device__ __forceinline__ unsigned bf16rn(float x) {
    unsigned u = __float_as_uint(x);
    return (u + 0x7FFFu + ((u >> 16) & 1u)) >> 16;
}
__device__ __forceinline__ unsigned pack2(float a, float b) {
    return bf16rn(a) | (bf16rn(b) << 16);
}
__device__ __forceinline__ float bflo(unsigned u) { return __uint_as_float(u << 16); }
__device__ __forceinline__ float bfhi(unsigned u) { return __uint_as_float(u & 0xFFFF0000u); }

__global__ void build_rowptr_k(const int* __restrict__ rows, int* __restrict__ rp) {
    int r = blockIdx.x * blockDim.x + threadIdx.x;
    if (r > NN) return;
    int lo = 0, hi = EE;
    while (lo < hi) {
        int mid = (lo + hi) >> 1;
        if (rows[mid] < r) lo = mid + 1; else hi = mid;
    }
    rp[r] = lo;
}

// inputs[b][n][f] fp32 -> xb[n][b*64+f] bf16 (node-major, matches y1/y2)
__global__ __launch_bounds__(256) void castxb_k(const float* __restrict__ inp,
                                                unsigned* __restrict__ xb) {
    int n = blockIdx.x, t = threadIdx.x;
    int b = t >> 4, f4 = (t & 15) << 2;
    float4 v = *(const float4*)(inp + ((size_t)b * NN + n) * 64 + f4);
    uint2 o; o.x = pack2(v.x, v.y); o.y = pack2(v.z, v.w);
    *(uint2*)(xb + (size_t)n * 512 + b * 32 + (f4 >> 1)) = o;
}

// Wt[o][k'] bf16, k' = m*64+f, Chebyshev fold: m0: W0-W2, m1: W1, m2: 2*W2
__global__ void wtprep_k(const float* __restrict__ W, unsigned short* __restrict__ wt) {
    int i = blockIdx.x * 256 + threadIdx.x;
    if (i >= 64 * 192) return;
    int o = i / 192, kp = i - o * 192;
    int m = kp >> 6, f = kp & 63;
    float w = W[(f * 3 + m) * 64 + o];
    if (m == 0) w -= W[(f * 3 + 2) * 64 + o];
    else if (m == 2) w += w;
    wt[o * WTP + kp] = (unsigned short)bf16rn(w);
}

// dst[n][c] = sum_e v * src[col][c], bf16 in/out, 16 slices of 64 ch (128B/row)
__global__ __launch_bounds__(256, 8) void spmm_bf16_k(
    const unsigned* __restrict__ src, const int* __restrict__ cols,
    const float* __restrict__ vals, const int* __restrict__ rp,
    unsigned* __restrict__ dst) {
    __shared__ int2 lcv[CAP];
    int s = blockIdx.y, t = threadIdx.x;
    int n0 = blockIdx.x * 32;
    int eBase = rp[n0];
    int eCap = min(rp[n0 + 32], eBase + CAP);
    for (int i = eBase + t; i < eCap; i += 256)
        lcv[i - eBase] = make_int2(cols[i], __float_as_int(vals[i]));
    __syncthreads();

    int node = n0 + (t >> 3);
    const unsigned* sp = src + s * 32 + (t & 7) * 4;
    int e0 = rp[node], e1 = rp[node + 1];
    int eL = min(e1, eCap);
    float a0=0,a1=0,a2=0,a3=0,a4=0,a5=0,a6=0,a7=0;
    #pragma unroll 2
    for (int e = e0; e < eL; ++e) {
        int2 cv = lcv[e - eBase];
        float v = __int_as_float(cv.y);
        uint4 w = *(const uint4*)(sp + (size_t)cv.x * 512);
        a0 += v * bflo(w.x); a1 += v * bfhi(w.x);
        a2 += v * bflo(w.y); a3 += v * bfhi(w.y);
        a4 += v * bflo(w.z); a5 += v * bfhi(w.z);
        a6 += v * bflo(w.w); a7 += v * bfhi(w.w);
    }
    for (int e = eL; e < e1; ++e) {   // overflow fallback (statistically never)
        int c = cols[e]; float v = vals[e];
        uint4 w = *(const uint4*)(sp + (size_t)c * 512);
        a0 += v * bflo(w.x); a1 += v * bfhi(w.x);
        a2 += v * bflo(w.y); a3 += v * bfhi(w.y);
        a4 += v * bflo(w.z); a5 += v * bfhi(w.z);
        a6 += v * bflo(w.w); a7 += v * bfhi(w.w);
    }
    uint4 o;
    o.x = pack2(a0, a1); o.y = pack2(a2, a3); o.z = pack2(a4, a5); o.w = pack2(a6, a7);
    *(uint4*)(dst + (size_t)node * 512 + s * 32 + (t & 7) * 4) = o;
}

// fallback (no ws room for xb): gather fp32 inputs directly, emit bf16 y1
__global__ __launch_bounds__(256, 8) void spmm1_f32_k(
    const float* __restrict__ inputs, const int* __restrict__ cols,
    const float* __restrict__ vals, const int* __restrict__ rp,
    unsigned* __restrict__ y1) {
    __shared__ int2 lcv[CAP];
    int s = blockIdx.y, t = threadIdx.x;
    int n0 = blockIdx.x * 32;
    int eBase = rp[n0];
    int eCap = min(rp[n0 + 32], eBase + CAP);
    for (int i = eBase + t; i < eCap; i += 256)
        lcv[i - eBase] = make_int2(cols[i], __float_as_int(vals[i]));
    __syncthreads();

    int node = n0 + (t >> 3);
    const float* sp = inputs + (size_t)(s >> 1) * NN * 64 + (s & 1) * 32 + (t & 7) * 4;
    int e0 = rp[node], e1 = rp[node + 1];
    int eL = min(e1, eCap);
    float4 acc = make_float4(0.f, 0.f, 0.f, 0.f);
    #pragma unroll 2
    for (int e = e0; e < eL; ++e) {
        int2 cv = lcv[e - eBase];
        float v = __int_as_float(cv.y);
        float4 xv = *(const float4*)(sp + (size_t)cv.x * 64);
        acc.x += v * xv.x; acc.y += v * xv.y; acc.z += v * xv.z; acc.w += v * xv.w;
    }
    for (int e = eL; e < e1; ++e) {
        int c = cols[e]; float v = vals[e];
        float4 xv = *(const float4*)(sp + (size_t)c * 64);
        acc.x += v * xv.x; acc.y += v * xv.y; acc.z += v * xv.z; acc.w += v * xv.w;
    }
    uint2 o; o.x = pack2(acc.x, acc.y); o.y = pack2(acc.z, acc.w);
    *(uint2*)(y1 + (size_t)node * 512 + (s >> 1) * 32 + (s & 1) * 16 + (t & 7) * 2) = o;
}

// MFMA GEMM: out[b*NN+n][o] = [x0|y1|y2](bf16) @ Wt + bias, fp32 out.
// block = 64 nodes x 64 out x 2 b-iters; 4 waves, each 16n x 64o, K=192.
__global__ __launch_bounds__(256) void gemm_k(
    const float* __restrict__ inputs, const unsigned* __restrict__ y1,
    const unsigned* __restrict__ y2, const unsigned short* __restrict__ wt,
    const float* __restrict__ bias, float* __restrict__ out) {
    __shared__ unsigned short wl[64 * WTP];   // 25.6 KB
    int t = threadIdx.x;
    for (int i = t; i < 1600; i += 256)
        ((uint4*)wl)[i] = ((const uint4*)wt)[i];
    __syncthreads();

    int w = t >> 6, l = t & 63;
    int lr = l & 15, lq = l >> 4;
    int n0 = blockIdx.x * 64 + w * 16;
    int nA = min(n0 + lr, NN - 1);   // clamped A-row (tail block)
    float bv0 = bias[lr], bv1 = bias[16 + lr], bv2 = bias[32 + lr], bv3 = bias[48 + lr];

    #pragma unroll
    for (int bb = 0; bb < 2; ++bb) {
        int b = blockIdx.y * 2 + bb;
        const float*    px = inputs + ((size_t)b * NN + nA) * 64 + lq * 8;
        const unsigned* p1 = y1 + (size_t)nA * 512 + b * 32 + lq * 4;
        const unsigned* p2 = y2 + (size_t)nA * 512 + b * 32 + lq * 4;

        short8 a[6];
        {
            float4 u0 = *(const float4*)(px);
            float4 u1 = *(const float4*)(px + 4);
            float4 u2 = *(const float4*)(px + 32);
            float4 u3 = *(const float4*)(px + 36);
            short8 t0, t1;
            t0[0] = (short)bf16rn(u0.x); t0[1] = (short)bf16rn(u0.y);
            t0[2] = (short)bf16rn(u0.z); t0[3] = (short)bf16rn(u0.w);
            t0[4] = (short)bf16rn(u1.x); t0[5] = (short)bf16rn(u1.y);
            t0[6] = (short)bf16rn(u1.z); t0[7] = (short)bf16rn(u1.w);
            t1[0] = (short)bf16rn(u2.x); t1[1] = (short)bf16rn(u2.y);
            t1[2] = (short)bf16rn(u2.z); t1[3] = (short)bf16rn(u2.w);
            t1[4] = (short)bf16rn(u3.x); t1[5] = (short)bf16rn(u3.y);
            t1[6] = (short)bf16rn(u3.z); t1[7] = (short)bf16rn(u3.w);
            a[0] = t0; a[1] = t1;
        }
        a[2] = *(const short8*)(p1);
        a[3] = *(const short8*)(p1 + 16);
        a[4] = *(const short8*)(p2);
        a[5] = *(const short8*)(p2 + 16);

        float4v acc0 = {0,0,0,0}, acc1 = {0,0,0,0}, acc2 = {0,0,0,0}, acc3 = {0,0,0,0};
        #pragma unroll
        for (int ks = 0; ks < 6; ++ks) {
            int kk = ks * 32 + lq * 8;
            short8 b0 = *(const short8*)&wl[(lr +  0) * WTP + kk];
            short8 b1 = *(const short8*)&wl[(lr + 16) * WTP + kk];
            short8 b2 = *(const short8*)&wl[(lr + 32) * WTP + kk];
            short8 b3 = *(const short8*)&wl[(lr + 48) * WTP + kk];
            acc0 = __builtin_amdgcn_mfma_f32_16x16x32_bf16(a[ks], b0, acc0, 0, 0, 0);
            acc1 = __builtin_amdgcn_mfma_f32_16x16x32_bf16(a[ks], b1, acc1, 0, 0, 0);
            acc2 = __builtin_amdgcn_mfma_f32_16x16x32_bf16(a[ks], b2, acc2, 0, 0, 0);
            acc3 = __builtin_amdgcn_mfma_f32_16x16x32_bf16(a[ks], b3, acc3, 0, 0, 0);
        }
        #pragma unroll
        for (int r = 0; r < 4; ++r) {
            int n = n0 + lq * 4 + r;
            if (n < NN) {
                float* po = out + ((size_t)b * NN + n) * 64;
                po[lr]      = acc0[r] + bv0;
                po[16 + lr] = acc1[r] + bv1;
                po[32 + lr] = acc2[r] + bv2;
                po[48 + lr] = acc3[r] + bv3;
            }
        }
    }
}

extern "C" void kernel_launch(void* const* d_in, const int* in_sizes, int n_in,
                              void* d_out, int out_size, void* d_ws, size_t ws_size,
                              hipStream_t stream) {
    const float* inputs  = (const float*)d_in[0];
    const int*   sp_rows = (const int*)d_in[1];
    const int*   sp_cols = (const int*)d_in[2];
    const float* sp_vals = (const float*)d_in[3];
    const float* weight  = (const float*)d_in[4];
    const float* biases  = (const float*)d_in[5];
    float* out = (float*)d_out;

    const size_t ybytes = (size_t)NN * 512 * 4;   // 40.96 MB per bf16 matrix
    char* base = (char*)d_ws;
    unsigned* y1 = (unsigned*)base;
    unsigned* y2 = (unsigned*)(base + ybytes);
    size_t off = 2 * ybytes;
    const size_t tail = ((size_t)(NN + 1) * 4 + 15 & ~(size_t)15) + 64 * WTP * 2 + 64;
    bool useXb = ws_size >= 3 * ybytes + tail;
    unsigned* xb = nullptr;
    if (useXb) { xb = (unsigned*)(base + off); off += ybytes; }
    int* rp = (int*)(base + off);
    off += ((size_t)(NN + 1) * 4 + 15) & ~(size_t)15;
    unsigned short* wt = (unsigned short*)(base + off);

    build_rowptr_k<<<79, 256, 0, stream>>>(sp_rows, rp);
    wtprep_k<<<48, 256, 0, stream>>>(weight, wt);
    if (useXb) {
        castxb_k<<<NN, 256, 0, stream>>>(inputs, xb);
        spmm_bf16_k<<<dim3(625, 16), 256, 0, stream>>>(xb, sp_cols, sp_vals, rp, y1);
    } else {
        spmm1_f32_k<<<dim3(625, 32), 256, 0, stream>>>(inputs, sp_cols, sp_vals, rp, y1);
    }
    spmm_bf16_k<<<dim3(625, 16), 256, 0, stream>>>(y1, sp_cols, sp_vals, rp, y2);
    gemm_k<<<dim3(313, 8), 256, 0, stream>>>(inputs, y1, y2, wt, biases, out);
}

// Round 5
// 352.822 us; speedup vs baseline: 3.2849x; 1.2410x over previous
//
#include <hip/hip_runtime.h>

#define NN 20000   // nodes
#define EE 640000  // edges
#define CAP 2048   // LDS edge-cache (int2) = 16 KB -> no occupancy throttle
#define WTP 200    // padded k-stride of transposed weight (breaks bank conflict)

typedef __attribute__((ext_vector_type(8))) short short8;
typedef __attribute__((ext_vector_type(4))) float float4v;
typedef __attribute__((ext_vector_type(2))) float float2v;

__device__ __forceinline__ unsigned bf16rn(float x) {
    unsigned u = __float_as_uint(x);
    return (u + 0x7FFFu + ((u >> 16) & 1u)) >> 16;
}
__device__ __forceinline__ unsigned pack2(float a, float b) {
    return bf16rn(a) | (bf16rn(b) << 16);
}
__device__ __forceinline__ float bflo(unsigned u) { return __uint_as_float(u << 16); }
__device__ __forceinline__ float bfhi(unsigned u) { return __uint_as_float(u & 0xFFFF0000u); }

__global__ void build_rowptr_k(const int* __restrict__ rows, int* __restrict__ rp) {
    int r = blockIdx.x * blockDim.x + threadIdx.x;
    if (r > NN) return;
    int lo = 0, hi = EE;
    while (lo < hi) {
        int mid = (lo + hi) >> 1;
        if (rows[mid] < r) lo = mid + 1; else hi = mid;
    }
    rp[r] = lo;
}

// inputs[b][n][f] fp32 -> xb[n][b*64+f] bf16 (node-major, matches y1/y2)
__global__ __launch_bounds__(256) void castxb_k(const float* __restrict__ inp,
                                                unsigned* __restrict__ xb) {
    int n = blockIdx.x, t = threadIdx.x;
    int b = t >> 4, f4 = (t & 15) << 2;
    float4 v = *(const float4*)(inp + ((size_t)b * NN + n) * 64 + f4);
    uint2 o; o.x = pack2(v.x, v.y); o.y = pack2(v.z, v.w);
    *(uint2*)(xb + (size_t)n * 512 + b * 32 + (f4 >> 1)) = o;
}

// Wt[o][k'] bf16, k' = m*64+f, Chebyshev fold: m0: W0-W2, m1: W1, m2: 2*W2
__global__ void wtprep_k(const float* __restrict__ W, unsigned short* __restrict__ wt) {
    int i = blockIdx.x * 256 + threadIdx.x;
    if (i >= 64 * 192) return;
    int o = i / 192, kp = i - o * 192;
    int m = kp >> 6, f = kp & 63;
    float w = W[(f * 3 + m) * 64 + o];
    if (m == 0) w -= W[(f * 3 + 2) * 64 + o];
    else if (m == 2) w += w;
    wt[o * WTP + kp] = (unsigned short)bf16rn(w);
}

__device__ __forceinline__ void accum(const uint4& q, int vbits,
                                      float2v& ac0, float2v& ac1,
                                      float2v& ac2, float2v& ac3) {
    float v_ = __int_as_float(vbits);
    float2v vv = {v_, v_};
    float2v p0 = {bflo(q.x), bfhi(q.x)};
    float2v p1 = {bflo(q.y), bfhi(q.y)};
    float2v p2 = {bflo(q.z), bfhi(q.z)};
    float2v p3 = {bflo(q.w), bfhi(q.w)};
    ac0 = __builtin_elementwise_fma(vv, p0, ac0);
    ac1 = __builtin_elementwise_fma(vv, p1, ac1);
    ac2 = __builtin_elementwise_fma(vv, p2, ac2);
    ac3 = __builtin_elementwise_fma(vv, p3, ac3);
}

// dst[n][c] = sum_e v * src[col][c], bf16 in/out.
// 1D grid of 10000 blocks, XCD-pinned slices: slice = (bid&7) + 8*((bid>>3)/625)
// so each XCD's 4MB L2 holds exactly one 2.56MB channel-slice at a time.
__global__ __launch_bounds__(256, 8) void spmm_bf16_k(
    const unsigned* __restrict__ src, const int* __restrict__ cols,
    const float* __restrict__ vals, const int* __restrict__ rp,
    unsigned* __restrict__ dst) {
    __shared__ int2 lcv[CAP];
    int bid = blockIdx.x;
    int xcd = bid & 7, j = bid >> 3;
    int chunk = j % 625;
    int s = xcd + ((j / 625) << 3);
    int t = threadIdx.x;
    int n0 = chunk * 32;
    int eBase = rp[n0];
    int eCap = min(rp[n0 + 32], eBase + CAP);
    for (int i = eBase + t; i < eCap; i += 256)
        lcv[i - eBase] = make_int2(cols[i], __float_as_int(vals[i]));
    __syncthreads();

    int node = n0 + (t >> 3);
    const unsigned* sp = src + s * 32 + (t & 7) * 4;
    int e0 = rp[node], e1 = rp[node + 1];
    int eL = min(e1, eCap);
    float2v ac0 = {0,0}, ac1 = {0,0}, ac2 = {0,0}, ac3 = {0,0};

    int e = e0;
    // 4-deep pipelined main loop: 4 independent gathers in flight per wave
    for (; e + 4 <= eL; e += 4) {
        int2 c0 = lcv[e - eBase],     c1 = lcv[e + 1 - eBase];
        int2 c2 = lcv[e + 2 - eBase], c3 = lcv[e + 3 - eBase];
        uint4 q0 = *(const uint4*)(sp + (size_t)c0.x * 512);
        uint4 q1 = *(const uint4*)(sp + (size_t)c1.x * 512);
        uint4 q2 = *(const uint4*)(sp + (size_t)c2.x * 512);
        uint4 q3 = *(const uint4*)(sp + (size_t)c3.x * 512);
        accum(q0, c0.y, ac0, ac1, ac2, ac3);
        accum(q1, c1.y, ac0, ac1, ac2, ac3);
        accum(q2, c2.y, ac0, ac1, ac2, ac3);
        accum(q3, c3.y, ac0, ac1, ac2, ac3);
    }
    for (; e < eL; ++e) {
        int2 cv = lcv[e - eBase];
        uint4 q = *(const uint4*)(sp + (size_t)cv.x * 512);
        accum(q, cv.y, ac0, ac1, ac2, ac3);
    }
    for (; e < e1; ++e) {   // overflow fallback (statistically never)
        int c = cols[e];
        uint4 q = *(const uint4*)(sp + (size_t)c * 512);
        accum(q, __float_as_int(vals[e]), ac0, ac1, ac2, ac3);
    }
    uint4 o;
    o.x = pack2(ac0[0], ac0[1]); o.y = pack2(ac1[0], ac1[1]);
    o.z = pack2(ac2[0], ac2[1]); o.w = pack2(ac3[0], ac3[1]);
    *(uint4*)(dst + (size_t)node * 512 + s * 32 + (t & 7) * 4) = o;
}

// fallback (no ws room for xb): gather fp32 inputs directly, emit bf16 y1
__global__ __launch_bounds__(256, 8) void spmm1_f32_k(
    const float* __restrict__ inputs, const int* __restrict__ cols,
    const float* __restrict__ vals, const int* __restrict__ rp,
    unsigned* __restrict__ y1) {
    __shared__ int2 lcv[CAP];
    int s = blockIdx.y, t = threadIdx.x;
    int n0 = blockIdx.x * 32;
    int eBase = rp[n0];
    int eCap = min(rp[n0 + 32], eBase + CAP);
    for (int i = eBase + t; i < eCap; i += 256)
        lcv[i - eBase] = make_int2(cols[i], __float_as_int(vals[i]));
    __syncthreads();

    int node = n0 + (t >> 3);
    const float* sp = inputs + (size_t)(s >> 1) * NN * 64 + (s & 1) * 32 + (t & 7) * 4;
    int e0 = rp[node], e1 = rp[node + 1];
    int eL = min(e1, eCap);
    float4 acc = make_float4(0.f, 0.f, 0.f, 0.f);
    #pragma unroll 2
    for (int e = e0; e < eL; ++e) {
        int2 cv = lcv[e - eBase];
        float v = __int_as_float(cv.y);
        float4 xv = *(const float4*)(sp + (size_t)cv.x * 64);
        acc.x += v * xv.x; acc.y += v * xv.y; acc.z += v * xv.z; acc.w += v * xv.w;
    }
    for (int e = eL; e < e1; ++e) {
        int c = cols[e]; float v = vals[e];
        float4 xv = *(const float4*)(sp + (size_t)c * 64);
        acc.x += v * xv.x; acc.y += v * xv.y; acc.z += v * xv.z; acc.w += v * xv.w;
    }
    uint2 o; o.x = pack2(acc.x, acc.y); o.y = pack2(acc.z, acc.w);
    *(uint2*)(y1 + (size_t)node * 512 + (s >> 1) * 32 + (s & 1) * 16 + (t & 7) * 2) = o;
}

// MFMA GEMM: out[b*NN+n][o] = [x0|y1|y2](bf16) @ Wt + bias, fp32 out.
// block = 64 nodes x 64 out x 2 b-iters; 4 waves, each 16n x 64o, K=192.
__global__ __launch_bounds__(256) void gemm_k(
    const float* __restrict__ inputs, const unsigned* __restrict__ xb,
    const unsigned* __restrict__ y1, const unsigned* __restrict__ y2,
    const unsigned short* __restrict__ wt, const float* __restrict__ bias,
    float* __restrict__ out) {
    __shared__ unsigned short wl[64 * WTP];   // 25.6 KB
    int t = threadIdx.x;
    for (int i = t; i < 1600; i += 256)
        ((uint4*)wl)[i] = ((const uint4*)wt)[i];
    __syncthreads();

    int w = t >> 6, l = t & 63;
    int lr = l & 15, lq = l >> 4;
    int n0 = blockIdx.x * 64 + w * 16;
    int nA = min(n0 + lr, NN - 1);   // clamped A-row (tail block)
    float bv0 = bias[lr], bv1 = bias[16 + lr], bv2 = bias[32 + lr], bv3 = bias[48 + lr];

    #pragma unroll
    for (int bb = 0; bb < 2; ++bb) {
        int b = blockIdx.y * 2 + bb;
        const unsigned* p1 = y1 + (size_t)nA * 512 + b * 32 + lq * 4;
        const unsigned* p2 = y2 + (size_t)nA * 512 + b * 32 + lq * 4;

        short8 a[6];
        if (xb) {
            const unsigned* p0 = xb + (size_t)nA * 512 + b * 32 + lq * 4;
            a[0] = *(const short8*)(p0);
            a[1] = *(const short8*)(p0 + 16);
        } else {
            const float* px = inputs + ((size_t)b * NN + nA) * 64 + lq * 8;
            float4 u0 = *(const float4*)(px);
            float4 u1 = *(const float4*)(px + 4);
            float4 u2 = *(const float4*)(px + 32);
            float4 u3 = *(const float4*)(px + 36);
            short8 t0, t1;
            t0[0] = (short)bf16rn(u0.x); t0[1] = (short)bf16rn(u0.y);
            t0[2] = (short)bf16rn(u0.z); t0[3] = (short)bf16rn(u0.w);
            t0[4] = (short)bf16rn(u1.x); t0[5] = (short)bf16rn(u1.y);
            t0[6] = (short)bf16rn(u1.z); t0[7] = (short)bf16rn(u1.w);
            t1[0] = (short)bf16rn(u2.x); t1[1] = (short)bf16rn(u2.y);
            t1[2] = (short)bf16rn(u2.z); t1[3] = (short)bf16rn(u2.w);
            t1[4] = (short)bf16rn(u3.x); t1[5] = (short)bf16rn(u3.y);
            t1[6] = (short)bf16rn(u3.z); t1[7] = (short)bf16rn(u3.w);
            a[0] = t0; a[1] = t1;
        }
        a[2] = *(const short8*)(p1);
        a[3] = *(const short8*)(p1 + 16);
        a[4] = *(const short8*)(p2);
        a[5] = *(const short8*)(p2 + 16);

        float4v acc0 = {0,0,0,0}, acc1 = {0,0,0,0}, acc2 = {0,0,0,0}, acc3 = {0,0,0,0};
        #pragma unroll
        for (int ks = 0; ks < 6; ++ks) {
            int kk = ks * 32 + lq * 8;
            short8 b0 = *(const short8*)&wl[(lr +  0) * WTP + kk];
            short8 b1 = *(const short8*)&wl[(lr + 16) * WTP + kk];
            short8 b2 = *(const short8*)&wl[(lr + 32) * WTP + kk];
            short8 b3 = *(const short8*)&wl[(lr + 48) * WTP + kk];
            acc0 = __builtin_amdgcn_mfma_f32_16x16x32_bf16(a[ks], b0, acc0, 0, 0, 0);
            acc1 = __builtin_amdgcn_mfma_f32_16x16x32_bf16(a[ks], b1, acc1, 0, 0, 0);
            acc2 = __builtin_amdgcn_mfma_f32_16x16x32_bf16(a[ks], b2, acc2, 0, 0, 0);
            acc3 = __builtin_amdgcn_mfma_f32_16x16x32_bf16(a[ks], b3, acc3, 0, 0, 0);
        }
        #pragma unroll
        for (int r = 0; r < 4; ++r) {
            int n = n0 + lq * 4 + r;
            if (n < NN) {
                float* po = out + ((size_t)b * NN + n) * 64;
                po[lr]      = acc0[r] + bv0;
                po[16 + lr] = acc1[r] + bv1;
                po[32 + lr] = acc2[r] + bv2;
                po[48 + lr] = acc3[r] + bv3;
            }
        }
    }
}

extern "C" void kernel_launch(void* const* d_in, const int* in_sizes, int n_in,
                              void* d_out, int out_size, void* d_ws, size_t ws_size,
                              hipStream_t stream) {
    const float* inputs  = (const float*)d_in[0];
    const int*   sp_rows = (const int*)d_in[1];
    const int*   sp_cols = (const int*)d_in[2];
    const float* sp_vals = (const float*)d_in[3];
    const float* weight  = (const float*)d_in[4];
    const float* biases  = (const float*)d_in[5];
    float* out = (float*)d_out;

    const size_t ybytes = (size_t)NN * 512 * 4;   // 40.96 MB per bf16 matrix
    char* base = (char*)d_ws;
    unsigned* y1 = (unsigned*)base;
    unsigned* y2 = (unsigned*)(base + ybytes);
    size_t off = 2 * ybytes;
    const size_t tail = (((size_t)(NN + 1) * 4 + 15) & ~(size_t)15) + 64 * WTP * 2 + 64;
    bool useXb = ws_size >= 3 * ybytes + tail;
    unsigned* xb = nullptr;
    if (useXb) { xb = (unsigned*)(base + off); off += ybytes; }
    int* rp = (int*)(base + off);
    off += ((size_t)(NN + 1) * 4 + 15) & ~(size_t)15;
    unsigned short* wt = (unsigned short*)(base + off);

    build_rowptr_k<<<79, 256, 0, stream>>>(sp_rows, rp);
    wtprep_k<<<48, 256, 0, stream>>>(weight, wt);
    if (useXb) {
        castxb_k<<<NN, 256, 0, stream>>>(inputs, xb);
        spmm_bf16_k<<<10000, 256, 0, stream>>>(xb, sp_cols, sp_vals, rp, y1);
    } else {
        spmm1_f32_k<<<dim3(625, 32), 256, 0, stream>>>(inputs, sp_cols, sp_vals, rp, y1);
    }
    spmm_bf16_k<<<10000, 256, 0, stream>>>(y1, sp_cols, sp_vals, rp, y2);
    gemm_k<<<dim3(313, 8), 256, 0, stream>>>(inputs, xb, y1, y2, wt, biases, out);
}